// Round 3
// baseline (492.800 us; speedup 1.0000x reference)
//
#include <hip/hip_runtime.h>

// Problem constants: B=512, D=1024, H1=512, H2=128
// Outputs (f32, concat): recover [512,1024], c2 [512,128], Jac [512,128,1024]
//
// R3 vs R2 (431.6 µs):
//  - A_all (64 MB) and build_A DELETED: Jac[b] = diag(s2p[b]) @ (W2 (.)col s1p[b]) @ W1.
//    Each Jac block builds its A-tile (W2*s1p, f32 math -> f16) in regs and ds_writes it
//    to a padded LDS tile; s2p applied as output row-scale in the epilogue.
//  - Jac kernel: 128x128 tile, BK=64 dbuf, 256 thr, 72 KB LDS -> 2 blocks/CU
//    (epilogue write overlaps other block's K-loop -- the R2 killer was 1 blk/CU).
//  - Nontemporal stores for the 268 MB Jac output + 2 MB recover (never re-read).
//  - HBM reads for the Jac launch ~0 (W2 256KB + W1T 1MB + s1p/s2p all L2-resident).

typedef _Float16 f16x8 __attribute__((ext_vector_type(8)));
typedef _Float16 f16x4 __attribute__((ext_vector_type(4)));
typedef float    f32x4 __attribute__((ext_vector_type(4)));
typedef float    f32x2 __attribute__((ext_vector_type(2)));

__device__ __forceinline__ void gld_lds16(const _Float16* src, _Float16* dst_wave_uniform) {
    __builtin_amdgcn_global_load_lds((const __attribute__((address_space(1))) unsigned int*)src,
                                     (__attribute__((address_space(3))) unsigned int*)dst_wave_uniform,
                                     16, 0, 0);
}

// ---------------- prep: W1 f32 -> W1T f16 (transposed [1024][512]) ----------------
__device__ __forceinline__ void prep_dev(int bx, const float* __restrict__ W1,
                                         _Float16* __restrict__ W1T) {
    __shared__ float tile[32][33];
    int dt = (bx & 31) * 32, kt = (bx >> 5) * 32;
    int tx = threadIdx.x & 31, ty = threadIdx.x >> 5;  // 32 x 8
    #pragma unroll
    for (int r = 0; r < 32; r += 8)
        tile[ty + r][tx] = W1[(kt + ty + r) * 1024 + dt + tx];
    __syncthreads();
    #pragma unroll
    for (int r = 0; r < 32; r += 8)
        W1T[(size_t)(dt + ty + r) * 512 + kt + tx] = (_Float16)tile[tx][ty + r];
}

// ---------------- small fp32 GEMMs (accuracy-critical path) ----------------
// 32x64 tile, 256 threads, per-thread 2x4, BK=32, register-prefetch pipeline.
// TRANSB=true: B is [N][K] (C=A@B^T).  EPI: 1 = sigmoid->C + Cd=s(1-s);  2 = sigmoid->Ch (f16)
template <int EPI, bool TRANSB>
__device__ void gemm_dev(const float* __restrict__ A, const float* __restrict__ Bm,
                         const float* __restrict__ bias,
                         float* __restrict__ C, float* __restrict__ Cd,
                         _Float16* __restrict__ Ch,
                         int M, int N, int K, int m0, int n0) {
    __shared__ __align__(16) float As[32][34];
    __shared__ __align__(16) float Bs[32][68];
    const int tid = threadIdx.x, tx = tid & 15, ty = tid >> 4;
    const int ka  = tid & 31, ma  = tid >> 5;
    const int kbt = tid & 31, nbt = tid >> 5;
    const int nbf = tid & 63, kbf = tid >> 6;
    float acc[2][4] = {};
    float rA[4], rB[8];

    #pragma unroll
    for (int r = 0; r < 4; ++r) rA[r] = A[(size_t)(m0 + ma + 8 * r) * K + ka];
    if (TRANSB) {
        #pragma unroll
        for (int r = 0; r < 8; ++r) rB[r] = Bm[(size_t)(n0 + nbt + 8 * r) * K + kbt];
    } else {
        #pragma unroll
        for (int r = 0; r < 8; ++r) rB[r] = Bm[(size_t)(kbf + 4 * r) * N + n0 + nbf];
    }

    for (int k0 = 0; k0 < K; k0 += 32) {
        #pragma unroll
        for (int r = 0; r < 4; ++r) As[ka][ma + 8 * r] = rA[r];
        if (TRANSB) {
            #pragma unroll
            for (int r = 0; r < 8; ++r) Bs[kbt][nbt + 8 * r] = rB[r];
        } else {
            #pragma unroll
            for (int r = 0; r < 8; ++r) Bs[kbf + 4 * r][nbf] = rB[r];
        }
        const int k1 = k0 + 32;
        if (k1 < K) {
            #pragma unroll
            for (int r = 0; r < 4; ++r) rA[r] = A[(size_t)(m0 + ma + 8 * r) * K + k1 + ka];
            if (TRANSB) {
                #pragma unroll
                for (int r = 0; r < 8; ++r) rB[r] = Bm[(size_t)(n0 + nbt + 8 * r) * K + k1 + kbt];
            } else {
                #pragma unroll
                for (int r = 0; r < 8; ++r) rB[r] = Bm[(size_t)(k1 + kbf + 4 * r) * N + n0 + nbf];
            }
        }
        __syncthreads();
        #pragma unroll
        for (int k = 0; k < 32; ++k) {
            f32x2 av = *(const f32x2*)&As[k][ty * 2];
            f32x4 bv = *(const f32x4*)&Bs[k][tx * 4];
            #pragma unroll
            for (int i = 0; i < 2; ++i)
                #pragma unroll
                for (int j = 0; j < 4; ++j)
                    acc[i][j] += av[i] * bv[j];
        }
        __syncthreads();
    }

    #pragma unroll
    for (int i = 0; i < 2; ++i) {
        int row = m0 + ty * 2 + i;
        #pragma unroll
        for (int j = 0; j < 4; ++j) {
            int col = n0 + tx * 4 + j;
            float z = acc[i][j] + bias[col];
            float s = 1.f / (1.f + __expf(-z));
            if constexpr (EPI == 1) {
                C[(size_t)row * N + col]  = s;
                Cd[(size_t)row * N + col] = s * (1.f - s);
            } else {
                Ch[(size_t)row * N + col] = (_Float16)s;
            }
        }
    }
}

// ---------------- fused launch wrappers ----------------
__global__ __launch_bounds__(256) void fused_prep_gemm1(const float* __restrict__ x,
                                                        const float* __restrict__ W1,
                                                        const float* __restrict__ b1,
                                                        _Float16* __restrict__ W1T,
                                                        float* __restrict__ c1,
                                                        float* __restrict__ s1p) {
    int bx = blockIdx.x;
    if (bx < 128) {   // long pole first: c1 GEMM (K=1024)
        gemm_dev<1, true>(x, W1, b1, c1, s1p, nullptr, 512, 512, 1024,
                          (bx >> 3) * 32, (bx & 7) * 64);
    } else {
        prep_dev(bx - 128, W1, W1T);
    }
}

__global__ __launch_bounds__(256) void gemm2_kernel(const float* __restrict__ c1,
                                                    const float* __restrict__ W2,
                                                    const float* __restrict__ b2,
                                                    float* __restrict__ out_c2,
                                                    float* __restrict__ s2p) {
    gemm_dev<1, true>(c1, W2, b2, out_c2, s2p, nullptr, 512, 128, 512,
                      blockIdx.y * 32, blockIdx.x * 64);
}

__global__ __launch_bounds__(256) void gemm3_kernel(const float* __restrict__ out_c2,
                                                    const float* __restrict__ W2,
                                                    const float* __restrict__ b3,
                                                    _Float16* __restrict__ c3h) {
    gemm_dev<2, false>(out_c2, W2, b3, nullptr, nullptr, c3h, 512, 512, 128,
                       (blockIdx.x >> 3) * 32, (blockIdx.x & 7) * 64);
}

// ---------------- fused MFMA: recover (32 blocks) + Jac (4096 blocks, no A_all) --------
// recover: Out = c3h @ W1T^T + br       (M=512, K=512, N=1024), 128^2 tiles
// jac:     Out[b] = diag(s2p[b]) @ (W2 .* s1p[b]) @ W1, via A-tile built in-block.
// 256 thr (4 waves, 2x2 of 64x64), BK=64. LDS ~72 KB -> 2 blocks/CU.
__global__ __launch_bounds__(256, 2) void jacF_fused(const _Float16* __restrict__ c3h,
                                                     const _Float16* __restrict__ W1T,
                                                     const float* __restrict__ W2,
                                                     const float* __restrict__ s1p,
                                                     const float* __restrict__ s2p,
                                                     const float* __restrict__ br,
                                                     float* __restrict__ out_rec,
                                                     float* __restrict__ out_jac) {
    __shared__ __align__(16) _Float16 Asl[2][128 * 72];  // jac: padded [row][72] (64 used +8 pad)
    __shared__ __align__(16) _Float16 Bsl[2][128 * 64];  // B tiles (W1T), linear, gld_lds
    __shared__ float S1[512];                            // jac: s1p[b]
    __shared__ float S2[128];                            // jac: s2p[b] slice / recover: bias

    const int tid = threadIdx.x;
    const int lane = tid & 63, wave = tid >> 6;
    const int wm = (wave >> 1) * 64, wn = (wave & 1) * 64;
    const int l15 = lane & 15, q = lane >> 4;
    const int bid = blockIdx.x;

    f32x4 acc[4][4];
    #pragma unroll
    for (int i = 0; i < 4; ++i)
        #pragma unroll
        for (int j = 0; j < 4; ++j) acc[i][j] = (f32x4){0.f, 0.f, 0.f, 0.f};

    if (bid < 32) {
        // ---------------- recover path (single-buffered m97 structure) ----------------
        const int m0 = (bid >> 3) * 128, n0 = (bid & 7) * 128;
        if (tid < 128) S2[tid] = br[n0 + tid];
        const int rbase = wave * 8 + (lane >> 3);
        const int kof   = (lane & 7) * 8;
        _Float16* As0 = &Asl[0][0];   // used as linear [128*64]
        _Float16* Bs0 = &Bsl[0][0];

        for (int k0 = 0; k0 < 512; k0 += 64) {
            #pragma unroll
            for (int r = 0; r < 4; ++r) {
                gld_lds16(c3h + (size_t)(m0 + r * 32 + rbase) * 512 + k0 + kof, As0 + (r * 32 + wave * 8) * 64);
                gld_lds16(W1T + (size_t)(n0 + r * 32 + rbase) * 512 + k0 + kof, Bs0 + (r * 32 + wave * 8) * 64);
            }
            __syncthreads();
            #pragma unroll
            for (int kk = 0; kk < 64; kk += 32) {
                f16x8 af[4], bf[4];
                #pragma unroll
                for (int i = 0; i < 4; ++i)
                    af[i] = *(const f16x8*)(As0 + (wm + i * 16 + l15) * 64 + kk + q * 8);
                #pragma unroll
                for (int j = 0; j < 4; ++j)
                    bf[j] = *(const f16x8*)(Bs0 + (wn + j * 16 + l15) * 64 + kk + q * 8);
                #pragma unroll
                for (int i = 0; i < 4; ++i)
                    #pragma unroll
                    for (int j = 0; j < 4; ++j)
                        acc[i][j] = __builtin_amdgcn_mfma_f32_16x16x32_f16(af[i], bf[j], acc[i][j], 0, 0, 0);
            }
            __syncthreads();
        }

        #pragma unroll
        for (int i = 0; i < 4; ++i) {
            #pragma unroll
            for (int rg = 0; rg < 4; ++rg) {
                int m = m0 + wm + i * 16 + q * 4 + rg;
                #pragma unroll
                for (int j = 0; j < 4; ++j) {
                    int dcol = wn + j * 16 + l15;
                    __builtin_nontemporal_store(acc[i][j][rg] + S2[dcol],
                                                out_rec + (size_t)m * 1024 + n0 + dcol);
                }
            }
        }
        return;
    }

    // ---------------- jac path ----------------
    const int jid = bid - 32;
    const int w = (jid & 7) * 512 + (jid >> 3);   // XCD-chunked bijection (4096 = 8*512)
    const int b = w >> 3, n0 = (w & 7) * 128;

    // stage per-batch vectors
    S1[tid]       = s1p[(size_t)b * 512 + tid];
    S1[tid + 256] = s1p[(size_t)b * 512 + 256 + tid];
    if (tid < 128) S2[tid] = s2p[(size_t)b * 128 + tid];

    // A build geometry: thread -> (row, k-half)
    const int arow = tid >> 1;             // 0..127
    const int akh  = (tid & 1) * 32;       // 0 or 32
    const float* W2r = W2 + arow * 512;
    // B staging (gld_lds, pre-swizzled source so swizzled read is conflict-free)
    const int srow = wave * 8 + (lane >> 3);
    const int skof = ((lane & 7) ^ (lane >> 3)) * 8;
    const _Float16* Bbase = W1T + (size_t)n0 * 512;
    const int swz = (l15 & 7) * 8;         // read-side XOR (row&7 == l15&7)

    f32x4 wv[8];

    auto ALOAD = [&](int t) {
        const int kb = t * 64 + akh;
        #pragma unroll
        for (int u = 0; u < 8; ++u) wv[u] = *(const f32x4*)(W2r + kb + u * 4);
    };
    auto BSTAGE = [&](int t) {
        const int buf = t & 1, kb = t * 64;
        #pragma unroll
        for (int r = 0; r < 4; ++r)
            gld_lds16(Bbase + (size_t)(r * 32 + srow) * 512 + kb + skof,
                      &Bsl[buf][(r * 32 + wave * 8) * 64]);
    };
    auto ADSW = [&](int t) {   // products in f32, convert, ds_write to padded tile
        const int buf = t & 1, kb = t * 64 + akh;
        #pragma unroll
        for (int j8 = 0; j8 < 4; ++j8) {
            f16x8 av;
            #pragma unroll
            for (int e = 0; e < 8; ++e) {
                int xx = j8 * 8 + e;
                av[e] = (_Float16)(wv[xx >> 2][xx & 3] * S1[kb + xx]);
            }
            *(f16x8*)(&Asl[buf][arow * 72 + akh + j8 * 8]) = av;
        }
    };

    // prologue
    ALOAD(0);
    BSTAGE(0);
    __syncthreads();           // S1/S2 visible (and B0 drained early — harmless)
    ADSW(0);
    ALOAD(1);
    BSTAGE(1);
    __syncthreads();           // A0 + B1 drained

    #pragma unroll 1
    for (int t = 0; t < 8; ++t) {
        const int buf = t & 1;
        const _Float16* As = &Asl[buf][0];
        const _Float16* Bs = &Bsl[buf][0];
        #pragma unroll
        for (int kk = 0; kk < 64; kk += 32) {
            f16x8 af[4], bf[4];
            #pragma unroll
            for (int i = 0; i < 4; ++i)
                af[i] = *(const f16x8*)(As + (wm + i * 16 + l15) * 72 + kk + q * 8);
            #pragma unroll
            for (int j = 0; j < 4; ++j)
                bf[j] = *(const f16x8*)(Bs + (wn + j * 16 + l15) * 64 + ((kk + q * 8) ^ swz));
            #pragma unroll
            for (int i = 0; i < 4; ++i)
                #pragma unroll
                for (int j = 0; j < 4; ++j)
                    acc[i][j] = __builtin_amdgcn_mfma_f32_16x16x32_f16(af[i], bf[j], acc[i][j], 0, 0, 0);
        }
        if (t < 7) ADSW(t + 1);            // into buf^1 (not being read this iter)
        __syncthreads();                   // all reads of buf done; A(t+1)/B(t+1) drained
        if (t < 6) { ALOAD(t + 2); BSTAGE(t + 2); }   // into buf (safe after barrier)
    }

    // epilogue: scale by s2p row factor, nontemporal stream out
    float* outb = out_jac + (size_t)b * (128 * 1024);
    #pragma unroll
    for (int i = 0; i < 4; ++i) {
        #pragma unroll
        for (int rg = 0; rg < 4; ++rg) {
            int h = wm + i * 16 + q * 4 + rg;
            float s = S2[h];
            #pragma unroll
            for (int j = 0; j < 4; ++j) {
                int d = n0 + wn + j * 16 + l15;
                __builtin_nontemporal_store(acc[i][j][rg] * s, outb + (size_t)h * 1024 + d);
            }
        }
    }
}

extern "C" void kernel_launch(void* const* d_in, const int* in_sizes, int n_in,
                              void* d_out, int out_size, void* d_ws, size_t ws_size,
                              hipStream_t stream) {
    const float* x  = (const float*)d_in[0];
    const float* W1 = (const float*)d_in[1];
    const float* b1 = (const float*)d_in[2];
    const float* W2 = (const float*)d_in[3];
    const float* b2 = (const float*)d_in[4];
    const float* b3 = (const float*)d_in[5];
    const float* br = (const float*)d_in[6];

    float* out_rec = (float*)d_out;               // 512*1024
    float* out_c2  = out_rec + 512 * 1024;        // 512*128
    float* out_jac = out_c2 + 512 * 128;          // 512*128*1024

    char* ws = (char*)d_ws;
    _Float16* W1T = (_Float16*)(ws);               // 1 MB   [1024][512]
    float*    c1  = (float*)(ws + 0x100000);       // 1 MB
    float*    s1p = (float*)(ws + 0x200000);       // 1 MB
    float*    s2p = (float*)(ws + 0x300000);       // 256 KB
    _Float16* c3h = (_Float16*)(ws + 0x340000);    // 512 KB (ends 0x3C0000)

    // L1: c1 GEMM (128 blocks) + W1T prep (512 blocks)
    fused_prep_gemm1<<<640, 256, 0, stream>>>(x, W1, b1, W1T, c1, s1p);
    // L2: c2 (+ s2p)
    gemm2_kernel<<<dim3(2, 16), 256, 0, stream>>>(c1, W2, b2, out_c2, s2p);
    // L3: c3h
    gemm3_kernel<<<128, 256, 0, stream>>>(out_c2, W2, b3, c3h);
    // L4: recover (32 blocks) + Jac (4096 blocks, A built in-block, no A_all)
    jacF_fused<<<4128, 256, 0, stream>>>(c3h, W1T, W2, s1p, s2p, br, out_rec, out_jac);
}

// Round 4
// 461.104 us; speedup vs baseline: 1.0687x; 1.0687x over previous
//
#include <hip/hip_runtime.h>

// Problem constants: B=512, D=1024, H1=512, H2=128
// Outputs (f32, concat): recover [512,1024], c2 [512,128], Jac [512,128,1024]
//
// R4 = R2 structure (A_all + build_A, best-so-far 431.6) with the occupancy fix:
//  - jac8: BK 64->32, LDS 132->65 KB -> 2 blocks/CU (16 waves/CU). Epilogue write
//    overlaps co-resident block's K-loop; 4 waves/SIMD hides ds_read/MFMA latency.
//  - counted vmcnt(4) (1 tile in flight), both-sides XOR swizzle over 4 slots (row&3).
//  - nontemporal stores for Jac/recover outputs (streaming, never re-read).

typedef _Float16 f16x8 __attribute__((ext_vector_type(8)));
typedef _Float16 f16x4 __attribute__((ext_vector_type(4)));
typedef float    f32x4 __attribute__((ext_vector_type(4)));
typedef float    f32x2 __attribute__((ext_vector_type(2)));

__device__ __forceinline__ void gld_lds16(const _Float16* src, _Float16* dst_wave_uniform) {
    __builtin_amdgcn_global_load_lds((const __attribute__((address_space(1))) unsigned int*)src,
                                     (__attribute__((address_space(3))) unsigned int*)dst_wave_uniform,
                                     16, 0, 0);
}

// ---------------- prep: W1 transpose->f16, W2 ->f16 (device body) ----------------
__device__ __forceinline__ void prep_dev(int bx, const float* __restrict__ W1,
                                         const float* __restrict__ W2,
                                         _Float16* __restrict__ W1T,
                                         _Float16* __restrict__ W2h) {
    if (bx < 512) {
        __shared__ float tile[32][33];
        int dt = (bx & 31) * 32, kt = (bx >> 5) * 32;
        int tx = threadIdx.x & 31, ty = threadIdx.x >> 5;  // 32 x 8
        #pragma unroll
        for (int r = 0; r < 32; r += 8)
            tile[ty + r][tx] = W1[(kt + ty + r) * 1024 + dt + tx];
        __syncthreads();
        #pragma unroll
        for (int r = 0; r < 32; r += 8)
            W1T[(size_t)(dt + ty + r) * 512 + kt + tx] = (_Float16)tile[tx][ty + r];
    } else {
        int i = (bx - 512) * 1024 + threadIdx.x * 4;  // 64 blocks cover 65536
        f32x4 v = *(const f32x4*)(W2 + i);
        f16x4 h;
        h.x = (_Float16)v.x; h.y = (_Float16)v.y; h.z = (_Float16)v.z; h.w = (_Float16)v.w;
        *(f16x4*)(W2h + i) = h;
    }
}

// ---------------- small fp32 GEMMs (accuracy-critical path) ----------------
// 32x64 tile, 256 threads, per-thread 2x4, BK=32, register-prefetch pipeline.
template <int EPI, bool TRANSB>
__device__ void gemm_dev(const float* __restrict__ A, const float* __restrict__ Bm,
                         const float* __restrict__ bias,
                         float* __restrict__ C, float* __restrict__ Cd,
                         _Float16* __restrict__ Ch,
                         int M, int N, int K, int m0, int n0) {
    __shared__ __align__(16) float As[32][34];
    __shared__ __align__(16) float Bs[32][68];
    const int tid = threadIdx.x, tx = tid & 15, ty = tid >> 4;
    const int ka  = tid & 31, ma  = tid >> 5;
    const int kbt = tid & 31, nbt = tid >> 5;
    const int nbf = tid & 63, kbf = tid >> 6;
    float acc[2][4] = {};
    float rA[4], rB[8];

    #pragma unroll
    for (int r = 0; r < 4; ++r) rA[r] = A[(size_t)(m0 + ma + 8 * r) * K + ka];
    if (TRANSB) {
        #pragma unroll
        for (int r = 0; r < 8; ++r) rB[r] = Bm[(size_t)(n0 + nbt + 8 * r) * K + kbt];
    } else {
        #pragma unroll
        for (int r = 0; r < 8; ++r) rB[r] = Bm[(size_t)(kbf + 4 * r) * N + n0 + nbf];
    }

    for (int k0 = 0; k0 < K; k0 += 32) {
        #pragma unroll
        for (int r = 0; r < 4; ++r) As[ka][ma + 8 * r] = rA[r];
        if (TRANSB) {
            #pragma unroll
            for (int r = 0; r < 8; ++r) Bs[kbt][nbt + 8 * r] = rB[r];
        } else {
            #pragma unroll
            for (int r = 0; r < 8; ++r) Bs[kbf + 4 * r][nbf] = rB[r];
        }
        const int k1 = k0 + 32;
        if (k1 < K) {
            #pragma unroll
            for (int r = 0; r < 4; ++r) rA[r] = A[(size_t)(m0 + ma + 8 * r) * K + k1 + ka];
            if (TRANSB) {
                #pragma unroll
                for (int r = 0; r < 8; ++r) rB[r] = Bm[(size_t)(n0 + nbt + 8 * r) * K + k1 + kbt];
            } else {
                #pragma unroll
                for (int r = 0; r < 8; ++r) rB[r] = Bm[(size_t)(k1 + kbf + 4 * r) * N + n0 + nbf];
            }
        }
        __syncthreads();
        #pragma unroll
        for (int k = 0; k < 32; ++k) {
            f32x2 av = *(const f32x2*)&As[k][ty * 2];
            f32x4 bv = *(const f32x4*)&Bs[k][tx * 4];
            #pragma unroll
            for (int i = 0; i < 2; ++i)
                #pragma unroll
                for (int j = 0; j < 4; ++j)
                    acc[i][j] += av[i] * bv[j];
        }
        __syncthreads();
    }

    #pragma unroll
    for (int i = 0; i < 2; ++i) {
        int row = m0 + ty * 2 + i;
        #pragma unroll
        for (int j = 0; j < 4; ++j) {
            int col = n0 + tx * 4 + j;
            float z = acc[i][j] + bias[col];
            float s = 1.f / (1.f + __expf(-z));
            if constexpr (EPI == 1) {
                C[(size_t)row * N + col]  = s;
                Cd[(size_t)row * N + col] = s * (1.f - s);
            } else {
                Ch[(size_t)row * N + col] = (_Float16)s;
            }
        }
    }
}

// ---------------- build A_all[b][h][k] = f16(s2p[b][h]*W2[h][k]*s1p[b][k]) ----------------
__device__ __forceinline__ void buildA_dev(int b, const float* __restrict__ W2,
                                           const float* __restrict__ s1p,
                                           const float* __restrict__ s2p,
                                           _Float16* __restrict__ A_all) {
    const int tid = threadIdx.x;
    __shared__ float S1[512];
    __shared__ float S2[128];
    S1[tid]       = s1p[(size_t)b * 512 + tid];
    S1[tid + 256] = s1p[(size_t)b * 512 + tid + 256];
    if (tid < 128) S2[tid] = s2p[(size_t)b * 128 + tid];
    __syncthreads();
    _Float16* out = A_all + (size_t)b * 65536;
    #pragma unroll 4
    for (int i = 0; i < 32; ++i) {
        int c = tid + 256 * i;
        int h = c >> 6, k8 = (c & 63) * 8;
        f32x4 w0 = *(const f32x4*)(W2 + h * 512 + k8);
        f32x4 w1 = *(const f32x4*)(W2 + h * 512 + k8 + 4);
        float s2 = S2[h];
        f16x8 o;
        o[0] = (_Float16)(s2 * w0.x * S1[k8 + 0]);
        o[1] = (_Float16)(s2 * w0.y * S1[k8 + 1]);
        o[2] = (_Float16)(s2 * w0.z * S1[k8 + 2]);
        o[3] = (_Float16)(s2 * w0.w * S1[k8 + 3]);
        o[4] = (_Float16)(s2 * w1.x * S1[k8 + 4]);
        o[5] = (_Float16)(s2 * w1.y * S1[k8 + 5]);
        o[6] = (_Float16)(s2 * w1.z * S1[k8 + 6]);
        o[7] = (_Float16)(s2 * w1.w * S1[k8 + 7]);
        *(f16x8*)(out + h * 512 + k8) = o;
    }
}

// ---------------- fused launch wrappers ----------------
__global__ __launch_bounds__(256) void fused_prep_gemm1(const float* __restrict__ x,
                                                        const float* __restrict__ W1,
                                                        const float* __restrict__ b1,
                                                        const float* __restrict__ W2,
                                                        _Float16* __restrict__ W1T,
                                                        _Float16* __restrict__ W2h,
                                                        float* __restrict__ c1,
                                                        float* __restrict__ s1p) {
    int bx = blockIdx.x;
    if (bx < 128) {
        gemm_dev<1, true>(x, W1, b1, c1, s1p, nullptr, 512, 512, 1024,
                          (bx >> 3) * 32, (bx & 7) * 64);
    } else {
        prep_dev(bx - 128, W1, W2, W1T, W2h);
    }
}

__global__ __launch_bounds__(256) void gemm2_kernel(const float* __restrict__ c1,
                                                    const float* __restrict__ W2,
                                                    const float* __restrict__ b2,
                                                    float* __restrict__ out_c2,
                                                    float* __restrict__ s2p) {
    gemm_dev<1, true>(c1, W2, b2, out_c2, s2p, nullptr, 512, 128, 512,
                      blockIdx.y * 32, blockIdx.x * 64);
}

__global__ __launch_bounds__(256) void gemm3_kernel(const float* __restrict__ out_c2,
                                                    const float* __restrict__ W2,
                                                    const float* __restrict__ b3,
                                                    _Float16* __restrict__ c3h) {
    gemm_dev<2, false>(out_c2, W2, b3, nullptr, nullptr, c3h, 512, 512, 128,
                       (blockIdx.x >> 3) * 32, (blockIdx.x & 7) * 64);
}

__global__ __launch_bounds__(256) void fused_mid(const float* __restrict__ out_c2,
                                                 const float* __restrict__ W2,
                                                 const float* __restrict__ b3,
                                                 _Float16* __restrict__ c3h,
                                                 const float* __restrict__ s1p,
                                                 const float* __restrict__ s2p,
                                                 _Float16* __restrict__ A_all) {
    int bx = blockIdx.x;
    if (bx < 128) {
        gemm_dev<2, false>(out_c2, W2, b3, nullptr, nullptr, c3h, 512, 512, 128,
                           (bx >> 3) * 32, (bx & 7) * 64);
    } else {
        buildA_dev(bx - 128, W2, s1p, s2p, A_all);
    }
}

// ---------------- 256^2 counted-vmcnt MFMA GEMM, BK=32, 2 blocks/CU ----------------
// Out = A @ W1T^T (+bias). recover = 8 blocks (M=512), Jac = 1024 blocks (M=65536).
// 512 thr (8 waves, 2m x 4n of 128x64), LDS 65 KB dbuf, vmcnt(4), both-sides XOR(row&3).
__global__ __launch_bounds__(512, 2) void jac8_kernel(const _Float16* __restrict__ c3h,
                                                      const _Float16* __restrict__ A_all,
                                                      const _Float16* __restrict__ W1T,
                                                      const float* __restrict__ br,
                                                      float* __restrict__ out_rec,
                                                      float* __restrict__ out_jac) {
    __shared__ __align__(16) _Float16 Asl[2][256 * 32];
    __shared__ __align__(16) _Float16 Bsl[2][256 * 32];
    __shared__ float BiasS[256];

    const int bid = blockIdx.x;
    const _Float16* A;
    float* Out;
    int m0, n0;
    bool has_bias;
    if (bid < 8) {                 // recover: M=512 -> 2 m-tiles x 4 n-tiles
        has_bias = true;
        A = c3h; Out = out_rec;
        m0 = (bid >> 2) * 256; n0 = (bid & 3) * 256;
    } else {                       // Jac: 1024 blocks, XCD-chunked bijection (bid%8 preserved)
        int jid = bid - 8;
        int w = (jid & 7) * 128 + (jid >> 3);   // XCD c owns w in [128c,128c+128)
        has_bias = false;
        A = A_all; Out = out_jac;
        m0 = (w >> 2) * 256; n0 = (w & 3) * 256;
    }

    const int tid = threadIdx.x;
    const int lane = tid & 63, wave = tid >> 6;
    const int wm = (wave >> 2) * 128, wn = (wave & 3) * 64;   // 2x4 wave grid, 128x64/wave
    const int l15 = lane & 15, q = lane >> 4;

    if (tid < 256) BiasS[tid] = has_bias ? br[n0 + tid] : 0.f;

    // staging: per tile 256 rows x 32 f16 per operand. Wave w, pass r: rows r*128+w*16..+16.
    // lane -> (row = l>>2, src col swizzled by row&3); LDS dest linear (wave-uniform + lane*16B).
    const int srow = lane >> 2;                              // 0..15
    const int skof = ((lane & 3) ^ ((lane >> 2) & 3)) * 8;   // f16 units, inverse-swizzled src
    const _Float16* Abase = A   + (size_t)m0 * 512;
    const _Float16* Bbase = W1T + (size_t)n0 * 512;

    auto STAGE = [&](int t) {
        const int buf = t & 1;
        const int kb = t * 32;
        #pragma unroll
        for (int r = 0; r < 2; ++r) {
            gld_lds16(Abase + (size_t)(r * 128 + wave * 16 + srow) * 512 + kb + skof,
                      &Asl[buf][(r * 128 + wave * 16) * 32]);
            gld_lds16(Bbase + (size_t)(r * 128 + wave * 16 + srow) * 512 + kb + skof,
                      &Bsl[buf][(r * 128 + wave * 16) * 32]);
        }
    };

    f32x4 acc[8][4];
    #pragma unroll
    for (int i = 0; i < 8; ++i)
        #pragma unroll
        for (int j = 0; j < 4; ++j) acc[i][j] = (f32x4){0.f, 0.f, 0.f, 0.f};

    STAGE(0);
    STAGE(1);

    const int swz = l15 & 3;     // read-side XOR (fragment row&3 == l15&3)

    #pragma unroll 1
    for (int t = 0; t < 16; ++t) {
        if (t < 15) asm volatile("s_waitcnt vmcnt(4)" ::: "memory");
        else        asm volatile("s_waitcnt vmcnt(0)" ::: "memory");
        __builtin_amdgcn_s_barrier();
        const int buf = t & 1;
        const _Float16* As = &Asl[buf][0];
        const _Float16* Bs = &Bsl[buf][0];

        f16x8 af[8], bf[4];
        #pragma unroll
        for (int i = 0; i < 8; ++i)
            af[i] = *(const f16x8*)(As + (wm + i * 16 + l15) * 32 + (q ^ swz) * 8);
        #pragma unroll
        for (int j = 0; j < 4; ++j)
            bf[j] = *(const f16x8*)(Bs + (wn + j * 16 + l15) * 32 + (q ^ swz) * 8);

        asm volatile("s_waitcnt lgkmcnt(0)" ::: "memory");
        __builtin_amdgcn_sched_barrier(0);     // fence: frags loaded before buf reuse/MFMA
        __builtin_amdgcn_s_barrier();          // all waves done reading buf
        if (t + 2 < 16) STAGE(t + 2);          // overwrite buf with tile t+2
        __builtin_amdgcn_sched_barrier(0);     // keep stage issue ahead of MFMA cluster

        __builtin_amdgcn_s_setprio(1);
        #pragma unroll
        for (int i = 0; i < 8; ++i)
            #pragma unroll
            for (int j = 0; j < 4; ++j)
                acc[i][j] = __builtin_amdgcn_mfma_f32_16x16x32_f16(af[i], bf[j], acc[i][j], 0, 0, 0);
        __builtin_amdgcn_s_setprio(0);
    }

    #pragma unroll
    for (int i = 0; i < 8; ++i) {
        #pragma unroll
        for (int rg = 0; rg < 4; ++rg) {
            int m = m0 + wm + i * 16 + q * 4 + rg;
            #pragma unroll
            for (int j = 0; j < 4; ++j) {
                int col = wn + j * 16 + l15;
                __builtin_nontemporal_store(acc[i][j][rg] + BiasS[col],
                                            Out + (size_t)m * 1024 + n0 + col);
            }
        }
    }
}

// ---------------- fallback path kernels (small workspace) ----------------
template <bool HAS_BIAS>
__global__ __launch_bounds__(256) void mfma_bt(const _Float16* __restrict__ Abase,
                                               const _Float16* __restrict__ Bmat,
                                               const float* __restrict__ bias,
                                               float* __restrict__ OutBase,
                                               int K, int N,
                                               long aBatch, long oBatch) {
    __shared__ __align__(16) _Float16 Asl[128 * 64];
    __shared__ __align__(16) _Float16 Bsl[128 * 64];
    __shared__ float Bias[128];
    const _Float16* A = Abase + (size_t)blockIdx.z * aBatch;
    float* Out = OutBase + (size_t)blockIdx.z * oBatch;
    const int m0 = blockIdx.y * 128, n0 = blockIdx.x * 128;
    const int tid = threadIdx.x;
    const int lane = tid & 63, wave = tid >> 6;
    const int wm = (wave >> 1) * 64, wn = (wave & 1) * 64;
    const int l15 = lane & 15, q = lane >> 4;

    if (HAS_BIAS && tid < 128) Bias[tid] = bias[n0 + tid];

    f32x4 acc[4][4];
    #pragma unroll
    for (int i = 0; i < 4; ++i)
        #pragma unroll
        for (int j = 0; j < 4; ++j) acc[i][j] = (f32x4){0.f, 0.f, 0.f, 0.f};

    const int rbase = wave * 8 + (lane >> 3);
    const int kof   = (lane & 7) * 8;

    for (int k0 = 0; k0 < K; k0 += 64) {
        #pragma unroll
        for (int r = 0; r < 4; ++r) {
            gld_lds16(A    + (size_t)(m0 + r * 32 + rbase) * K + k0 + kof, Asl + (r * 32 + wave * 8) * 64);
            gld_lds16(Bmat + (size_t)(n0 + r * 32 + rbase) * K + k0 + kof, Bsl + (r * 32 + wave * 8) * 64);
        }
        __syncthreads();
        #pragma unroll
        for (int kk = 0; kk < 64; kk += 32) {
            f16x8 af[4], bf[4];
            #pragma unroll
            for (int i = 0; i < 4; ++i)
                af[i] = *(const f16x8*)(Asl + (wm + i * 16 + l15) * 64 + kk + q * 8);
            #pragma unroll
            for (int j = 0; j < 4; ++j)
                bf[j] = *(const f16x8*)(Bsl + (wn + j * 16 + l15) * 64 + kk + q * 8);
            #pragma unroll
            for (int i = 0; i < 4; ++i)
                #pragma unroll
                for (int j = 0; j < 4; ++j)
                    acc[i][j] = __builtin_amdgcn_mfma_f32_16x16x32_f16(af[i], bf[j], acc[i][j], 0, 0, 0);
        }
        __syncthreads();
    }

    #pragma unroll
    for (int i = 0; i < 4; ++i) {
        #pragma unroll
        for (int rg = 0; rg < 4; ++rg) {
            int m = m0 + wm + i * 16 + q * 4 + rg;
            #pragma unroll
            for (int j = 0; j < 4; ++j) {
                int dcol = wn + j * 16 + l15;
                float v = acc[i][j][rg];
                if (HAS_BIAS) v += Bias[dcol];
                Out[(size_t)m * N + n0 + dcol] = v;
            }
        }
    }
}

__global__ __launch_bounds__(256) void jac_kernel(const _Float16* __restrict__ W2h,
                                                  const _Float16* __restrict__ W1T,
                                                  const float* __restrict__ s1p,
                                                  const float* __restrict__ s2p,
                                                  float* __restrict__ Jac) {
    __shared__ __align__(16) _Float16 Asl[128 * 64];
    __shared__ __align__(16) _Float16 Bsl[128 * 64];
    __shared__ float Ssl[128];
    const int b  = blockIdx.y;
    const int n0 = blockIdx.x * 128;
    const int tid = threadIdx.x;
    const int lane = tid & 63, wave = tid >> 6;
    const int wm = (wave >> 1) * 64, wn = (wave & 1) * 64;
    const int l15 = lane & 15, q = lane >> 4;

    if (tid < 128) Ssl[tid] = s2p[b * 128 + tid];

    f32x4 acc[4][4];
    #pragma unroll
    for (int i = 0; i < 4; ++i)
        #pragma unroll
        for (int j = 0; j < 4; ++j) acc[i][j] = (f32x4){0.f, 0.f, 0.f, 0.f};

    const int ah  = tid >> 4;
    const int akq = (tid & 15) * 4;
    const int rbase = wave * 8 + (lane >> 3);
    const int kof   = (lane & 7) * 8;

    for (int k0 = 0; k0 < 512; k0 += 64) {
        f32x4 s4 = *(const f32x4*)(s1p + (size_t)b * 512 + k0 + akq);
        f16x4 s4h;
        s4h.x = (_Float16)s4.x; s4h.y = (_Float16)s4.y;
        s4h.z = (_Float16)s4.z; s4h.w = (_Float16)s4.w;
        #pragma unroll
        for (int r = 0; r < 8; ++r) {
            int h = ah + r * 16;
            f16x4 w4 = *(const f16x4*)(W2h + (size_t)h * 512 + k0 + akq);
            *(f16x4*)(Asl + h * 64 + akq) = w4 * s4h;
        }
        #pragma unroll
        for (int r = 0; r < 4; ++r)
            gld_lds16(W1T + (size_t)(n0 + r * 32 + rbase) * 512 + k0 + kof,
                      Bsl + (r * 32 + wave * 8) * 64);
        __syncthreads();

        #pragma unroll
        for (int kk = 0; kk < 64; kk += 32) {
            f16x8 af[4], bf[4];
            #pragma unroll
            for (int i = 0; i < 4; ++i)
                af[i] = *(const f16x8*)(Asl + (wm + i * 16 + l15) * 64 + kk + q * 8);
            #pragma unroll
            for (int j = 0; j < 4; ++j)
                bf[j] = *(const f16x8*)(Bsl + (wn + j * 16 + l15) * 64 + kk + q * 8);
            #pragma unroll
            for (int i = 0; i < 4; ++i)
                #pragma unroll
                for (int j = 0; j < 4; ++j)
                    acc[i][j] = __builtin_amdgcn_mfma_f32_16x16x32_f16(af[i], bf[j], acc[i][j], 0, 0, 0);
        }
        __syncthreads();
    }

    float* outb = Jac + (size_t)b * (128 * 1024);
    #pragma unroll
    for (int i = 0; i < 4; ++i) {
        #pragma unroll
        for (int rg = 0; rg < 4; ++rg) {
            int h = wm + i * 16 + q * 4 + rg;
            float s = Ssl[h];
            #pragma unroll
            for (int j = 0; j < 4; ++j) {
                int d = n0 + wn + j * 16 + l15;
                outb[(size_t)h * 1024 + d] = acc[i][j][rg] * s;
            }
        }
    }
}

extern "C" void kernel_launch(void* const* d_in, const int* in_sizes, int n_in,
                              void* d_out, int out_size, void* d_ws, size_t ws_size,
                              hipStream_t stream) {
    const float* x  = (const float*)d_in[0];
    const float* W1 = (const float*)d_in[1];
    const float* b1 = (const float*)d_in[2];
    const float* W2 = (const float*)d_in[3];
    const float* b2 = (const float*)d_in[4];
    const float* b3 = (const float*)d_in[5];
    const float* br = (const float*)d_in[6];

    float* out_rec = (float*)d_out;               // 512*1024
    float* out_c2  = out_rec + 512 * 1024;        // 512*128
    float* out_jac = out_c2 + 512 * 128;          // 512*128*1024

    char* ws = (char*)d_ws;
    _Float16* W1T   = (_Float16*)(ws);             // 1 MB   [1024][512]
    _Float16* W2h   = (_Float16*)(ws + 0x100000);  // 128 KB [128][512]
    float*    c1    = (float*)(ws + 0x120000);     // 1 MB
    float*    s1p   = (float*)(ws + 0x220000);     // 1 MB
    float*    s2p   = (float*)(ws + 0x320000);     // 256 KB
    _Float16* c3h   = (_Float16*)(ws + 0x360000);  // 512 KB (ends 0x3E0000)
    _Float16* A_all = (_Float16*)(ws + 0x400000);  // 64 MB  [512][128][512]
    const bool big_ws = ws_size >= (size_t)0x4400000;

    // L1: c1 GEMM (128 blocks) + prep (576 blocks)
    fused_prep_gemm1<<<704, 256, 0, stream>>>(x, W1, b1, W2, W1T, W2h, c1, s1p);
    // L2: c2 (+ s2p)
    gemm2_kernel<<<dim3(2, 16), 256, 0, stream>>>(c1, W2, b2, out_c2, s2p);
    if (big_ws) {
        // L3: c3h GEMM (128 blocks) + build_A (512 blocks)
        fused_mid<<<640, 256, 0, stream>>>(out_c2, W2, b3, c3h, s1p, s2p, A_all);
        // L4: recover (8 blocks) + Jac (1024 blocks), BK=32, 2 blocks/CU
        jac8_kernel<<<1032, 512, 0, stream>>>(c3h, A_all, W1T, br, out_rec, out_jac);
    } else {
        gemm3_kernel<<<128, 256, 0, stream>>>(out_c2, W2, b3, c3h);
        mfma_bt<true><<<dim3(8, 4, 1), 256, 0, stream>>>(c3h, W1T, br, out_rec, 512, 1024, 0, 0);
        jac_kernel<<<dim3(8, 512), 256, 0, stream>>>(W2h, W1T, s1p, s2p, out_jac);
    }
}

// Round 5
// 405.500 us; speedup vs baseline: 1.2153x; 1.1371x over previous
//
#include <hip/hip_runtime.h>

// Problem constants: B=512, D=1024, H1=512, H2=128
// Outputs (f32, concat): recover [512,1024], c2 [512,128], Jac [512,128,1024]
//
// R5 vs R2 (431.6 best) / R4 (461):
//  - A_all + build_A DELETED. jac blocks stage W2h k-tiles (16 KB/step, identical for
//    every block -> always L2-hot) with the PROVEN both-sides XOR swizzle, and build
//    A-fragments in registers: af = w2_frag * s1_frag (4 v_pk_mul_f16), s1p from a 1 KB
//    LDS f16 vector (broadcast reads). s2p applied as f32 row-scale in the epilogue.
//    (R3 failed because it rebuilt A via ds_write per n-tile inside the K-loop; this
//    version adds only register-level pk_muls to the proven R1 single-buffered loop.)
//  - jac kernel: 128x128 tile, BK=64, single-buffered (m97 2-barrier), 256 thr,
//    ~33.5 KB LDS -> 4 blocks/CU (16 waves/CU, m114 implicit overlap).
//  - recover folded in as 32 blocks of the same kernel (generic A = c3h, bias epilogue).
//  - nontemporal stores for the streaming 270 MB output.
//  - workspace need drops to ~4 MB.

typedef _Float16 f16x8 __attribute__((ext_vector_type(8)));
typedef _Float16 f16x4 __attribute__((ext_vector_type(4)));
typedef float    f32x4 __attribute__((ext_vector_type(4)));
typedef float    f32x2 __attribute__((ext_vector_type(2)));

__device__ __forceinline__ void gld_lds16(const _Float16* src, _Float16* dst_wave_uniform) {
    __builtin_amdgcn_global_load_lds((const __attribute__((address_space(1))) unsigned int*)src,
                                     (__attribute__((address_space(3))) unsigned int*)dst_wave_uniform,
                                     16, 0, 0);
}

// ---------------- prep: W1 transpose->f16, W2 ->f16 ----------------
__device__ __forceinline__ void prep_dev(int bx, const float* __restrict__ W1,
                                         const float* __restrict__ W2,
                                         _Float16* __restrict__ W1T,
                                         _Float16* __restrict__ W2h) {
    if (bx < 512) {
        __shared__ float tile[32][33];
        int dt = (bx & 31) * 32, kt = (bx >> 5) * 32;
        int tx = threadIdx.x & 31, ty = threadIdx.x >> 5;  // 32 x 8
        #pragma unroll
        for (int r = 0; r < 32; r += 8)
            tile[ty + r][tx] = W1[(kt + ty + r) * 1024 + dt + tx];
        __syncthreads();
        #pragma unroll
        for (int r = 0; r < 32; r += 8)
            W1T[(size_t)(dt + ty + r) * 512 + kt + tx] = (_Float16)tile[tx][ty + r];
    } else {
        int i = (bx - 512) * 1024 + threadIdx.x * 4;  // 64 blocks cover 65536
        f32x4 v = *(const f32x4*)(W2 + i);
        f16x4 h;
        h.x = (_Float16)v.x; h.y = (_Float16)v.y; h.z = (_Float16)v.z; h.w = (_Float16)v.w;
        *(f16x4*)(W2h + i) = h;
    }
}

// ---------------- small fp32 GEMMs (accuracy-critical path) ----------------
// 32x64 tile, 256 threads, per-thread 2x4, BK=32, register-prefetch pipeline.
template <int EPI, bool TRANSB>
__device__ void gemm_dev(const float* __restrict__ A, const float* __restrict__ Bm,
                         const float* __restrict__ bias,
                         float* __restrict__ C, float* __restrict__ Cd,
                         _Float16* __restrict__ Ch,
                         int M, int N, int K, int m0, int n0) {
    __shared__ __align__(16) float As[32][34];
    __shared__ __align__(16) float Bs[32][68];
    const int tid = threadIdx.x, tx = tid & 15, ty = tid >> 4;
    const int ka  = tid & 31, ma  = tid >> 5;
    const int kbt = tid & 31, nbt = tid >> 5;
    const int nbf = tid & 63, kbf = tid >> 6;
    float acc[2][4] = {};
    float rA[4], rB[8];

    #pragma unroll
    for (int r = 0; r < 4; ++r) rA[r] = A[(size_t)(m0 + ma + 8 * r) * K + ka];
    if (TRANSB) {
        #pragma unroll
        for (int r = 0; r < 8; ++r) rB[r] = Bm[(size_t)(n0 + nbt + 8 * r) * K + kbt];
    } else {
        #pragma unroll
        for (int r = 0; r < 8; ++r) rB[r] = Bm[(size_t)(kbf + 4 * r) * N + n0 + nbf];
    }

    for (int k0 = 0; k0 < K; k0 += 32) {
        #pragma unroll
        for (int r = 0; r < 4; ++r) As[ka][ma + 8 * r] = rA[r];
        if (TRANSB) {
            #pragma unroll
            for (int r = 0; r < 8; ++r) Bs[kbt][nbt + 8 * r] = rB[r];
        } else {
            #pragma unroll
            for (int r = 0; r < 8; ++r) Bs[kbf + 4 * r][nbf] = rB[r];
        }
        const int k1 = k0 + 32;
        if (k1 < K) {
            #pragma unroll
            for (int r = 0; r < 4; ++r) rA[r] = A[(size_t)(m0 + ma + 8 * r) * K + k1 + ka];
            if (TRANSB) {
                #pragma unroll
                for (int r = 0; r < 8; ++r) rB[r] = Bm[(size_t)(n0 + nbt + 8 * r) * K + k1 + kbt];
            } else {
                #pragma unroll
                for (int r = 0; r < 8; ++r) rB[r] = Bm[(size_t)(k1 + kbf + 4 * r) * N + n0 + nbf];
            }
        }
        __syncthreads();
        #pragma unroll
        for (int k = 0; k < 32; ++k) {
            f32x2 av = *(const f32x2*)&As[k][ty * 2];
            f32x4 bv = *(const f32x4*)&Bs[k][tx * 4];
            #pragma unroll
            for (int i = 0; i < 2; ++i)
                #pragma unroll
                for (int j = 0; j < 4; ++j)
                    acc[i][j] += av[i] * bv[j];
        }
        __syncthreads();
    }

    #pragma unroll
    for (int i = 0; i < 2; ++i) {
        int row = m0 + ty * 2 + i;
        #pragma unroll
        for (int j = 0; j < 4; ++j) {
            int col = n0 + tx * 4 + j;
            float z = acc[i][j] + bias[col];
            float s = 1.f / (1.f + __expf(-z));
            if constexpr (EPI == 1) {
                C[(size_t)row * N + col]  = s;
                Cd[(size_t)row * N + col] = s * (1.f - s);
            } else {
                Ch[(size_t)row * N + col] = (_Float16)s;
            }
        }
    }
}

// ---------------- fused launch wrappers ----------------
__global__ __launch_bounds__(256) void fused_prep_gemm1(const float* __restrict__ x,
                                                        const float* __restrict__ W1,
                                                        const float* __restrict__ b1,
                                                        const float* __restrict__ W2,
                                                        _Float16* __restrict__ W1T,
                                                        _Float16* __restrict__ W2h,
                                                        float* __restrict__ c1,
                                                        float* __restrict__ s1p) {
    int bx = blockIdx.x;
    if (bx < 128) {
        gemm_dev<1, true>(x, W1, b1, c1, s1p, nullptr, 512, 512, 1024,
                          (bx >> 3) * 32, (bx & 7) * 64);
    } else {
        prep_dev(bx - 128, W1, W2, W1T, W2h);
    }
}

__global__ __launch_bounds__(256) void gemm2_kernel(const float* __restrict__ c1,
                                                    const float* __restrict__ W2,
                                                    const float* __restrict__ b2,
                                                    float* __restrict__ out_c2,
                                                    float* __restrict__ s2p) {
    gemm_dev<1, true>(c1, W2, b2, out_c2, s2p, nullptr, 512, 128, 512,
                      blockIdx.y * 32, blockIdx.x * 64);
}

__global__ __launch_bounds__(256) void gemm3_kernel(const float* __restrict__ out_c2,
                                                    const float* __restrict__ W2,
                                                    const float* __restrict__ b3,
                                                    _Float16* __restrict__ c3h) {
    gemm_dev<2, false>(out_c2, W2, b3, nullptr, nullptr, c3h, 512, 512, 128,
                       (blockIdx.x >> 3) * 32, (blockIdx.x & 7) * 64);
}

// ---------------- fused MFMA: recover (32 blocks) + Jac (4096 blocks, no A_all) -------
// jac:     Out[b] = diag(s2p[b]) @ (W2h .*col s1p[b]) @ W1T^T
//          A-tile staged = W2h k-slice (batch-independent, 16 KB/step, L2-hot);
//          s1p multiplied into A-fragments in registers (v_pk_mul_f16).
// recover: Out = c3h @ W1T^T + br (M=512), generic A staging from c3h.
// 128x128 tile, BK=64 single-buffered, 256 thr (4 waves 2x2 of 64x64), ~33.5 KB LDS.
__global__ __launch_bounds__(256, 4) void jacW_fused(const _Float16* __restrict__ c3h,
                                                     const _Float16* __restrict__ W2h,
                                                     const _Float16* __restrict__ W1T,
                                                     const float* __restrict__ s1p,
                                                     const float* __restrict__ s2p,
                                                     const float* __restrict__ br,
                                                     float* __restrict__ out_rec,
                                                     float* __restrict__ out_jac) {
    __shared__ __align__(16) _Float16 Wsl[128 * 64];  // A-src tile (W2h slice or c3h rows)
    __shared__ __align__(16) _Float16 Bsl[128 * 64];  // W1T tile
    __shared__ _Float16 S1h[512];                     // jac: s1p[b] as f16
    __shared__ float    S2s[128];                     // jac: s2p[b] / recover: bias

    const int tid = threadIdx.x;
    const int lane = tid & 63, wave = tid >> 6;
    const int wm = (wave >> 1) * 64, wn = (wave & 1) * 64;
    const int l15 = lane & 15, q = lane >> 4;
    const int bid = blockIdx.x;

    const bool is_rec = (bid < 32);
    const _Float16* Abase;
    float* outp;
    int n0, b = 0, m0 = 0;
    if (is_rec) {
        m0 = (bid >> 3) * 128; n0 = (bid & 7) * 128;
        Abase = c3h + (size_t)m0 * 512;
        outp = out_rec + (size_t)m0 * 1024;
        if (tid < 128) S2s[tid] = br[n0 + tid];
    } else {
        int jid = bid - 32;
        int w = (jid & 7) * 512 + (jid >> 3);   // XCD-chunked bijection (4096 = 8*512)
        b = w >> 3; n0 = (w & 7) * 128;
        Abase = W2h;                            // batch-independent A source!
        outp = out_jac + (size_t)b * (128 * 1024);
        S1h[tid]       = (_Float16)s1p[(size_t)b * 512 + tid];
        S1h[tid + 256] = (_Float16)s1p[(size_t)b * 512 + 256 + tid];
        if (tid < 128) S2s[tid] = s2p[(size_t)b * 128 + tid];
    }

    // staging geometry (proven R2 swizzle): row = r*32 + wave*8 + (lane>>3),
    // source k-slot = (lane&7)^(lane>>3); LDS dest linear. Read slot = (kk/8+q)^(row&7).
    const int srow = wave * 8 + (lane >> 3);
    const int skof = ((lane & 7) ^ (lane >> 3)) * 8;
    const _Float16* Bbase = W1T + (size_t)n0 * 512;

    f32x4 acc[4][4];
    #pragma unroll
    for (int i = 0; i < 4; ++i)
        #pragma unroll
        for (int j = 0; j < 4; ++j) acc[i][j] = (f32x4){0.f, 0.f, 0.f, 0.f};

    for (int t = 0; t < 8; ++t) {
        const int kb = t * 64;
        #pragma unroll
        for (int r = 0; r < 4; ++r) {
            gld_lds16(Abase + (size_t)(r * 32 + srow) * 512 + kb + skof, Wsl + (r * 32 + wave * 8) * 64);
            gld_lds16(Bbase + (size_t)(r * 32 + srow) * 512 + kb + skof, Bsl + (r * 32 + wave * 8) * 64);
        }
        __syncthreads();
        #pragma unroll
        for (int kk = 0; kk < 64; kk += 32) {
            f16x8 af[4], bf[4], sf;
            if (!is_rec)
                sf = *(const f16x8*)(&S1h[kb + kk + q * 8]);   // broadcast per q-group
            #pragma unroll
            for (int i = 0; i < 4; ++i) {
                f16x8 wf = *(const f16x8*)(Wsl + (wm + i * 16 + l15) * 64 + ((kk + q * 8) ^ ((l15 & 7) * 8)));
                af[i] = is_rec ? wf : wf * sf;                 // 4x v_pk_mul_f16
            }
            #pragma unroll
            for (int j = 0; j < 4; ++j)
                bf[j] = *(const f16x8*)(Bsl + (wn + j * 16 + l15) * 64 + ((kk + q * 8) ^ ((l15 & 7) * 8)));
            #pragma unroll
            for (int i = 0; i < 4; ++i)
                #pragma unroll
                for (int j = 0; j < 4; ++j)
                    acc[i][j] = __builtin_amdgcn_mfma_f32_16x16x32_f16(af[i], bf[j], acc[i][j], 0, 0, 0);
        }
        __syncthreads();
    }

    #pragma unroll
    for (int i = 0; i < 4; ++i) {
        #pragma unroll
        for (int rg = 0; rg < 4; ++rg) {
            int ml = wm + i * 16 + q * 4 + rg;           // local row
            float rs = is_rec ? 1.f : S2s[ml];
            #pragma unroll
            for (int j = 0; j < 4; ++j) {
                int cl = wn + j * 16 + l15;              // local col
                float v = acc[i][j][rg] * rs;
                if (is_rec) v += S2s[cl];
                __builtin_nontemporal_store(v, outp + (size_t)ml * 1024 + n0 + cl);
            }
        }
    }
}

extern "C" void kernel_launch(void* const* d_in, const int* in_sizes, int n_in,
                              void* d_out, int out_size, void* d_ws, size_t ws_size,
                              hipStream_t stream) {
    const float* x  = (const float*)d_in[0];
    const float* W1 = (const float*)d_in[1];
    const float* b1 = (const float*)d_in[2];
    const float* W2 = (const float*)d_in[3];
    const float* b2 = (const float*)d_in[4];
    const float* b3 = (const float*)d_in[5];
    const float* br = (const float*)d_in[6];

    float* out_rec = (float*)d_out;               // 512*1024
    float* out_c2  = out_rec + 512 * 1024;        // 512*128
    float* out_jac = out_c2 + 512 * 128;          // 512*128*1024

    char* ws = (char*)d_ws;
    _Float16* W1T = (_Float16*)(ws);               // 1 MB   [1024][512]
    _Float16* W2h = (_Float16*)(ws + 0x100000);    // 128 KB [128][512]
    float*    c1  = (float*)(ws + 0x120000);       // 1 MB
    float*    s1p = (float*)(ws + 0x220000);       // 1 MB
    float*    s2p = (float*)(ws + 0x320000);       // 256 KB
    _Float16* c3h = (_Float16*)(ws + 0x360000);    // 512 KB (ends 0x3E0000, ~3.9 MB total)

    // L1: c1 GEMM (128 blocks) + prep (576 blocks)
    fused_prep_gemm1<<<704, 256, 0, stream>>>(x, W1, b1, W2, W1T, W2h, c1, s1p);
    // L2: c2 (+ s2p)
    gemm2_kernel<<<dim3(2, 16), 256, 0, stream>>>(c1, W2, b2, out_c2, s2p);
    // L3: c3h
    gemm3_kernel<<<128, 256, 0, stream>>>(out_c2, W2, b3, c3h);
    // L4: recover (32 blocks) + Jac (4096 blocks, A built from W2h*s1p in registers)
    jacW_fused<<<4128, 256, 0, stream>>>(c3h, W2h, W1T, s1p, s2p, br, out_rec, out_jac);
}

// Round 6
// 404.347 us; speedup vs baseline: 1.2188x; 1.0029x over previous
//
#include <hip/hip_runtime.h>

// Problem constants: B=512, D=1024, H1=512, H2=128
// Outputs (f32, concat): recover [512,1024], c2 [512,128], Jac [512,128,1024]
//
// R6 vs R5 (405.5):
//  - jac blocks now compute G=2 BATCHES per n-tile: the staged A-tile (W2h k-slice) and
//    B-tile (W1T) are batch-independent, so each LDS fragment read feeds MFMAs for two
//    batches (af = wf*s1p[bA], then wf*s1p[bB]). LDS-reads-per-MFMA halve (0.5 -> 0.25),
//    flipping the m97-structure's LDS-pipe bound into a matrix-pipe bound.
//  - acc doubles -> ~200 VGPR, __launch_bounds__(256,2): 2 blocks/CU, write overlap kept.
//  - grid 4128 -> 2080 (32 recover + 2048 jac). Everything else R5-verbatim.

typedef _Float16 f16x8 __attribute__((ext_vector_type(8)));
typedef _Float16 f16x4 __attribute__((ext_vector_type(4)));
typedef float    f32x4 __attribute__((ext_vector_type(4)));
typedef float    f32x2 __attribute__((ext_vector_type(2)));

__device__ __forceinline__ void gld_lds16(const _Float16* src, _Float16* dst_wave_uniform) {
    __builtin_amdgcn_global_load_lds((const __attribute__((address_space(1))) unsigned int*)src,
                                     (__attribute__((address_space(3))) unsigned int*)dst_wave_uniform,
                                     16, 0, 0);
}

// ---------------- prep: W1 transpose->f16, W2 ->f16 ----------------
__device__ __forceinline__ void prep_dev(int bx, const float* __restrict__ W1,
                                         const float* __restrict__ W2,
                                         _Float16* __restrict__ W1T,
                                         _Float16* __restrict__ W2h) {
    if (bx < 512) {
        __shared__ float tile[32][33];
        int dt = (bx & 31) * 32, kt = (bx >> 5) * 32;
        int tx = threadIdx.x & 31, ty = threadIdx.x >> 5;  // 32 x 8
        #pragma unroll
        for (int r = 0; r < 32; r += 8)
            tile[ty + r][tx] = W1[(kt + ty + r) * 1024 + dt + tx];
        __syncthreads();
        #pragma unroll
        for (int r = 0; r < 32; r += 8)
            W1T[(size_t)(dt + ty + r) * 512 + kt + tx] = (_Float16)tile[tx][ty + r];
    } else {
        int i = (bx - 512) * 1024 + threadIdx.x * 4;  // 64 blocks cover 65536
        f32x4 v = *(const f32x4*)(W2 + i);
        f16x4 h;
        h.x = (_Float16)v.x; h.y = (_Float16)v.y; h.z = (_Float16)v.z; h.w = (_Float16)v.w;
        *(f16x4*)(W2h + i) = h;
    }
}

// ---------------- small fp32 GEMMs (accuracy-critical path) ----------------
// 32x64 tile, 256 threads, per-thread 2x4, BK=32, register-prefetch pipeline.
template <int EPI, bool TRANSB>
__device__ void gemm_dev(const float* __restrict__ A, const float* __restrict__ Bm,
                         const float* __restrict__ bias,
                         float* __restrict__ C, float* __restrict__ Cd,
                         _Float16* __restrict__ Ch,
                         int M, int N, int K, int m0, int n0) {
    __shared__ __align__(16) float As[32][34];
    __shared__ __align__(16) float Bs[32][68];
    const int tid = threadIdx.x, tx = tid & 15, ty = tid >> 4;
    const int ka  = tid & 31, ma  = tid >> 5;
    const int kbt = tid & 31, nbt = tid >> 5;
    const int nbf = tid & 63, kbf = tid >> 6;
    float acc[2][4] = {};
    float rA[4], rB[8];

    #pragma unroll
    for (int r = 0; r < 4; ++r) rA[r] = A[(size_t)(m0 + ma + 8 * r) * K + ka];
    if (TRANSB) {
        #pragma unroll
        for (int r = 0; r < 8; ++r) rB[r] = Bm[(size_t)(n0 + nbt + 8 * r) * K + kbt];
    } else {
        #pragma unroll
        for (int r = 0; r < 8; ++r) rB[r] = Bm[(size_t)(kbf + 4 * r) * N + n0 + nbf];
    }

    for (int k0 = 0; k0 < K; k0 += 32) {
        #pragma unroll
        for (int r = 0; r < 4; ++r) As[ka][ma + 8 * r] = rA[r];
        if (TRANSB) {
            #pragma unroll
            for (int r = 0; r < 8; ++r) Bs[kbt][nbt + 8 * r] = rB[r];
        } else {
            #pragma unroll
            for (int r = 0; r < 8; ++r) Bs[kbf + 4 * r][nbf] = rB[r];
        }
        const int k1 = k0 + 32;
        if (k1 < K) {
            #pragma unroll
            for (int r = 0; r < 4; ++r) rA[r] = A[(size_t)(m0 + ma + 8 * r) * K + k1 + ka];
            if (TRANSB) {
                #pragma unroll
                for (int r = 0; r < 8; ++r) rB[r] = Bm[(size_t)(n0 + nbt + 8 * r) * K + k1 + kbt];
            } else {
                #pragma unroll
                for (int r = 0; r < 8; ++r) rB[r] = Bm[(size_t)(k1 + kbf + 4 * r) * N + n0 + nbf];
            }
        }
        __syncthreads();
        #pragma unroll
        for (int k = 0; k < 32; ++k) {
            f32x2 av = *(const f32x2*)&As[k][ty * 2];
            f32x4 bv = *(const f32x4*)&Bs[k][tx * 4];
            #pragma unroll
            for (int i = 0; i < 2; ++i)
                #pragma unroll
                for (int j = 0; j < 4; ++j)
                    acc[i][j] += av[i] * bv[j];
        }
        __syncthreads();
    }

    #pragma unroll
    for (int i = 0; i < 2; ++i) {
        int row = m0 + ty * 2 + i;
        #pragma unroll
        for (int j = 0; j < 4; ++j) {
            int col = n0 + tx * 4 + j;
            float z = acc[i][j] + bias[col];
            float s = 1.f / (1.f + __expf(-z));
            if constexpr (EPI == 1) {
                C[(size_t)row * N + col]  = s;
                Cd[(size_t)row * N + col] = s * (1.f - s);
            } else {
                Ch[(size_t)row * N + col] = (_Float16)s;
            }
        }
    }
}

// ---------------- fused launch wrappers ----------------
__global__ __launch_bounds__(256) void fused_prep_gemm1(const float* __restrict__ x,
                                                        const float* __restrict__ W1,
                                                        const float* __restrict__ b1,
                                                        const float* __restrict__ W2,
                                                        _Float16* __restrict__ W1T,
                                                        _Float16* __restrict__ W2h,
                                                        float* __restrict__ c1,
                                                        float* __restrict__ s1p) {
    int bx = blockIdx.x;
    if (bx < 128) {
        gemm_dev<1, true>(x, W1, b1, c1, s1p, nullptr, 512, 512, 1024,
                          (bx >> 3) * 32, (bx & 7) * 64);
    } else {
        prep_dev(bx - 128, W1, W2, W1T, W2h);
    }
}

__global__ __launch_bounds__(256) void gemm2_kernel(const float* __restrict__ c1,
                                                    const float* __restrict__ W2,
                                                    const float* __restrict__ b2,
                                                    float* __restrict__ out_c2,
                                                    float* __restrict__ s2p) {
    gemm_dev<1, true>(c1, W2, b2, out_c2, s2p, nullptr, 512, 128, 512,
                      blockIdx.y * 32, blockIdx.x * 64);
}

__global__ __launch_bounds__(256) void gemm3_kernel(const float* __restrict__ out_c2,
                                                    const float* __restrict__ W2,
                                                    const float* __restrict__ b3,
                                                    _Float16* __restrict__ c3h) {
    gemm_dev<2, false>(out_c2, W2, b3, nullptr, nullptr, c3h, 512, 512, 128,
                       (blockIdx.x >> 3) * 32, (blockIdx.x & 7) * 64);
}

// ---------------- fused MFMA: recover (32 blocks) + Jac (2048 blocks, G=2 batches) ----
// jac:  block = 2 batches x one 128-wide n-tile.
//       A-tile staged = W2h k-slice (batch-independent, L2-hot); each wf/bf fragment
//       read feeds MFMAs for BOTH batches (af = wf * s1p[bA], then wf * s1p[bB]).
//       s2p applied as f32 row-scale in the epilogue.
// recover: Out = c3h @ W1T^T + br (M=512), R5-verbatim.
// 128x128(x2) tile, BK=64 single-buffered, 256 thr, ~35 KB LDS, ~200 VGPR -> 2 blk/CU.
__global__ __launch_bounds__(256, 2) void jacW_fused(const _Float16* __restrict__ c3h,
                                                     const _Float16* __restrict__ W2h,
                                                     const _Float16* __restrict__ W1T,
                                                     const float* __restrict__ s1p,
                                                     const float* __restrict__ s2p,
                                                     const float* __restrict__ br,
                                                     float* __restrict__ out_rec,
                                                     float* __restrict__ out_jac) {
    __shared__ __align__(16) _Float16 Wsl[128 * 64];  // A-src tile (W2h slice or c3h rows)
    __shared__ __align__(16) _Float16 Bsl[128 * 64];  // W1T tile
    __shared__ _Float16 S1h[2][512];                  // jac: s1p[bA], s1p[bB] as f16
    __shared__ float    S2s[2][128];                  // jac: s2p[bA], s2p[bB] / rec: bias

    const int tid = threadIdx.x;
    const int lane = tid & 63, wave = tid >> 6;
    const int wm = (wave >> 1) * 64, wn = (wave & 1) * 64;
    const int l15 = lane & 15, q = lane >> 4;
    const int bid = blockIdx.x;

    // staging geometry (proven R2/R5 swizzle): row = r*32 + wave*8 + (lane>>3),
    // source k-slot = (lane&7)^(lane>>3); LDS dest linear. Read slot = (kk/8+q)^(row&7).
    const int srow = wave * 8 + (lane >> 3);
    const int skof = ((lane & 7) ^ (lane >> 3)) * 8;

    if (bid < 32) {
        // ---------------- recover path (R5-verbatim) ----------------
        const int m0 = (bid >> 3) * 128, n0 = (bid & 7) * 128;
        const _Float16* Abase = c3h + (size_t)m0 * 512;
        const _Float16* Bbase = W1T + (size_t)n0 * 512;
        float* outp = out_rec + (size_t)m0 * 1024;
        if (tid < 128) S2s[0][tid] = br[n0 + tid];

        f32x4 acc[4][4];
        #pragma unroll
        for (int i = 0; i < 4; ++i)
            #pragma unroll
            for (int j = 0; j < 4; ++j) acc[i][j] = (f32x4){0.f, 0.f, 0.f, 0.f};

        for (int t = 0; t < 8; ++t) {
            const int kb = t * 64;
            #pragma unroll
            for (int r = 0; r < 4; ++r) {
                gld_lds16(Abase + (size_t)(r * 32 + srow) * 512 + kb + skof, Wsl + (r * 32 + wave * 8) * 64);
                gld_lds16(Bbase + (size_t)(r * 32 + srow) * 512 + kb + skof, Bsl + (r * 32 + wave * 8) * 64);
            }
            __syncthreads();
            #pragma unroll
            for (int kk = 0; kk < 64; kk += 32) {
                f16x8 af[4], bf[4];
                #pragma unroll
                for (int i = 0; i < 4; ++i)
                    af[i] = *(const f16x8*)(Wsl + (wm + i * 16 + l15) * 64 + ((kk + q * 8) ^ ((l15 & 7) * 8)));
                #pragma unroll
                for (int j = 0; j < 4; ++j)
                    bf[j] = *(const f16x8*)(Bsl + (wn + j * 16 + l15) * 64 + ((kk + q * 8) ^ ((l15 & 7) * 8)));
                #pragma unroll
                for (int i = 0; i < 4; ++i)
                    #pragma unroll
                    for (int j = 0; j < 4; ++j)
                        acc[i][j] = __builtin_amdgcn_mfma_f32_16x16x32_f16(af[i], bf[j], acc[i][j], 0, 0, 0);
            }
            __syncthreads();
        }

        #pragma unroll
        for (int i = 0; i < 4; ++i) {
            #pragma unroll
            for (int rg = 0; rg < 4; ++rg) {
                int ml = wm + i * 16 + q * 4 + rg;
                #pragma unroll
                for (int j = 0; j < 4; ++j) {
                    int cl = wn + j * 16 + l15;
                    __builtin_nontemporal_store(acc[i][j][rg] + S2s[0][cl],
                                                outp + (size_t)ml * 1024 + n0 + cl);
                }
            }
        }
        return;
    }

    // ---------------- jac path: G=2 batches per block ----------------
    const int jid = bid - 32;
    const int w = (jid & 7) * 256 + (jid >> 3);   // XCD-chunked bijection (2048 = 8*256)
    const int pair = w >> 3, n0 = (w & 7) * 128;
    const int bA = pair * 2;

    // stage per-batch vectors (each thread: 2 elems per batch)
    S1h[0][tid]       = (_Float16)s1p[(size_t)bA * 512 + tid];
    S1h[0][tid + 256] = (_Float16)s1p[(size_t)bA * 512 + 256 + tid];
    S1h[1][tid]       = (_Float16)s1p[(size_t)(bA + 1) * 512 + tid];
    S1h[1][tid + 256] = (_Float16)s1p[(size_t)(bA + 1) * 512 + 256 + tid];
    if (tid < 128) S2s[0][tid] = s2p[(size_t)bA * 128 + tid];
    else           S2s[1][tid - 128] = s2p[(size_t)(bA + 1) * 128 + (tid - 128)];

    const _Float16* Bbase = W1T + (size_t)n0 * 512;

    f32x4 accA[4][4], accB[4][4];
    #pragma unroll
    for (int i = 0; i < 4; ++i)
        #pragma unroll
        for (int j = 0; j < 4; ++j) {
            accA[i][j] = (f32x4){0.f, 0.f, 0.f, 0.f};
            accB[i][j] = (f32x4){0.f, 0.f, 0.f, 0.f};
        }

    for (int t = 0; t < 8; ++t) {
        const int kb = t * 64;
        #pragma unroll
        for (int r = 0; r < 4; ++r) {
            gld_lds16(W2h   + (size_t)(r * 32 + srow) * 512 + kb + skof, Wsl + (r * 32 + wave * 8) * 64);
            gld_lds16(Bbase + (size_t)(r * 32 + srow) * 512 + kb + skof, Bsl + (r * 32 + wave * 8) * 64);
        }
        __syncthreads();
        #pragma unroll
        for (int kk = 0; kk < 64; kk += 32) {
            const f16x8 sfA = *(const f16x8*)(&S1h[0][kb + kk + q * 8]);   // broadcast
            const f16x8 sfB = *(const f16x8*)(&S1h[1][kb + kk + q * 8]);
            f16x8 bf[4];
            #pragma unroll
            for (int j = 0; j < 4; ++j)
                bf[j] = *(const f16x8*)(Bsl + (wn + j * 16 + l15) * 64 + ((kk + q * 8) ^ ((l15 & 7) * 8)));
            #pragma unroll
            for (int i = 0; i < 4; ++i) {
                const f16x8 wf = *(const f16x8*)(Wsl + (wm + i * 16 + l15) * 64 + ((kk + q * 8) ^ ((l15 & 7) * 8)));
                f16x8 af = wf * sfA;                       // 4x v_pk_mul_f16
                #pragma unroll
                for (int j = 0; j < 4; ++j)
                    accA[i][j] = __builtin_amdgcn_mfma_f32_16x16x32_f16(af, bf[j], accA[i][j], 0, 0, 0);
                af = wf * sfB;
                #pragma unroll
                for (int j = 0; j < 4; ++j)
                    accB[i][j] = __builtin_amdgcn_mfma_f32_16x16x32_f16(af, bf[j], accB[i][j], 0, 0, 0);
            }
        }
        __syncthreads();
    }

    // epilogue: s2p row-scale, nontemporal stream out (both batches)
    float* outA = out_jac + (size_t)bA * (128 * 1024);
    float* outB = outA + (128 * 1024);
    #pragma unroll
    for (int i = 0; i < 4; ++i) {
        #pragma unroll
        for (int rg = 0; rg < 4; ++rg) {
            int ml = wm + i * 16 + q * 4 + rg;
            float rsA = S2s[0][ml], rsB = S2s[1][ml];
            #pragma unroll
            for (int j = 0; j < 4; ++j) {
                int cl = wn + j * 16 + l15;
                __builtin_nontemporal_store(accA[i][j][rg] * rsA, outA + (size_t)ml * 1024 + n0 + cl);
                __builtin_nontemporal_store(accB[i][j][rg] * rsB, outB + (size_t)ml * 1024 + n0 + cl);
            }
        }
    }
}

extern "C" void kernel_launch(void* const* d_in, const int* in_sizes, int n_in,
                              void* d_out, int out_size, void* d_ws, size_t ws_size,
                              hipStream_t stream) {
    const float* x  = (const float*)d_in[0];
    const float* W1 = (const float*)d_in[1];
    const float* b1 = (const float*)d_in[2];
    const float* W2 = (const float*)d_in[3];
    const float* b2 = (const float*)d_in[4];
    const float* b3 = (const float*)d_in[5];
    const float* br = (const float*)d_in[6];

    float* out_rec = (float*)d_out;               // 512*1024
    float* out_c2  = out_rec + 512 * 1024;        // 512*128
    float* out_jac = out_c2 + 512 * 128;          // 512*128*1024

    char* ws = (char*)d_ws;
    _Float16* W1T = (_Float16*)(ws);               // 1 MB   [1024][512]
    _Float16* W2h = (_Float16*)(ws + 0x100000);    // 128 KB [128][512]
    float*    c1  = (float*)(ws + 0x120000);       // 1 MB
    float*    s1p = (float*)(ws + 0x220000);       // 1 MB
    float*    s2p = (float*)(ws + 0x320000);       // 256 KB
    _Float16* c3h = (_Float16*)(ws + 0x360000);    // 512 KB (ends 0x3E0000, ~3.9 MB total)

    // L1: c1 GEMM (128 blocks) + prep (576 blocks)
    fused_prep_gemm1<<<704, 256, 0, stream>>>(x, W1, b1, W2, W1T, W2h, c1, s1p);
    // L2: c2 (+ s2p)
    gemm2_kernel<<<dim3(2, 16), 256, 0, stream>>>(c1, W2, b2, out_c2, s2p);
    // L3: c3h
    gemm3_kernel<<<128, 256, 0, stream>>>(out_c2, W2, b3, c3h);
    // L4: recover (32 blocks) + Jac (2048 blocks, G=2 batches/block)
    jacW_fused<<<2080, 256, 0, stream>>>(c3h, W2h, W1T, s1p, s2p, br, out_rec, out_jac);
}